// Round 11
// baseline (282.188 us; speedup 1.0000x reference)
//
#include <hip/hip_runtime.h>
#include <hip/hip_bf16.h>

// MHA forward. B=4, T=2048, D=1024, H=16, Hd=64. Inputs auto-detected f32/bf16.
// convert x + transpose weights (fused) -> QKV GEMM (128x256/BK64, TRIPLE-buffer
// LDS, depth-4-group prefetch, counted vmcnt(9); +bias; Q pre-scaled by log2e/8;
// V -> vT in-epilogue) -> flash attention v12 (KVBLK=128, lsum via ones-MFMA)
// -> out GEMM (same template, 256 blocks = 1 round, dyn f32/bf16 out).
// R4: never cap occupancy via __launch_bounds__ 2nd arg (spill disaster).
// R5: don't interleave P LDS writes into PV chain. R6: keep S live range to one kb.
// R7: all single-buffer variants stall ~120us on per-tile barrier drain.
// R9: manual instr-order pinning defeats compiler sched (m141).
// R10: no-LDS attention REGRESSED 3.5x: K-row stride 6KB; LDS IS the coalescer.
// R12: lp-as-f32x4 REGRESSED: acc vectorization perturbed regalloc.
// R15: lsum-via-ones-MFMA WIN: attn 101->90.3, Mfma 43.7->56.9 (+VALU ~ 96%
//     issue-saturated -> v12 near this structure's ceiling). VGPR 88->60.
//     PV-as-K=32 needs cross-quad permlane repack of P, cost ~ gain. Skip.
// R16: KVBLK=64 FAILED: grid only 512 blocks -> still 2 resident/CU.
// R17: gemm1 128x256/BK64 768 blocks = 3 exact rounds: -6us. R18: gemm2 same
//     template, 256 blocks = 1 round: -2us.
// R19 (this round): ALL gemm structures (128^2/256^2/128x256) converge at
//     ~600TF / Mfma 22% -> structure-independent; diagnosis: vmcnt-stall
//     equilibrium. Prefetch distance = 2 phases ~ 700cy < 900cy HBM latency,
//     so every phase stalls until distance ~ latency (phase ~700cy). Fix:
//     3-buffer LDS (144KB, 1 block/CU unchanged), stage group n+4, vmcnt(9)
//     -> distance 3 phases > latency even at compute-bound pace.

typedef __bf16 bf16_t;
typedef __bf16 bf16x8 __attribute__((ext_vector_type(8)));
typedef float f32x4 __attribute__((ext_vector_type(4)));
typedef short short4v __attribute__((ext_vector_type(4)));

#if __has_builtin(__builtin_amdgcn_mfma_f32_16x16x16_bf16)
typedef __bf16 bf16x4 __attribute__((ext_vector_type(4)));
#define MFMA_PV(va, vb, c) __builtin_amdgcn_mfma_f32_16x16x16_bf16( \
    __builtin_bit_cast(bf16x4, (va)), __builtin_bit_cast(bf16x4, (vb)), (c), 0, 0, 0)
#else
#define MFMA_PV(va, vb, c) __builtin_amdgcn_mfma_f32_16x16x16bf16_1k((va), (vb), (c), 0, 0, 0)
#endif

#define DMODEL 1024
#define NH     16
#define HD     64
#define BATCH  4
#define SEQ    2048
#define NTOK   (BATCH * SEQ)      // 8192
#define NOUT   (NTOK * DMODEL)    // 8388608
#define CEXP   0.1803368801111204f   // log2(e)/sqrt(64)

__device__ __forceinline__ void async_ld16(void* lds, const void* g) {
  __builtin_amdgcn_global_load_lds(
      (const __attribute__((address_space(1))) void*)g,
      (__attribute__((address_space(3))) void*)lds, 16, 0, 0);
}

// ------------------------------------------------------------- dtype sniff + biases
__global__ __launch_bounds__(256) void sniff_dtype(
    const uint4* __restrict__ x, int* __restrict__ flag,
    const void* __restrict__ sq, const void* __restrict__ so,
    float* __restrict__ dq, float* __restrict__ dofs) {
  int t = threadIdx.x;
  int nanish = 0, zc = 0;
  for (int j = 0; j < 4; ++j) {
    uint4 w = x[t + j * 256];
    unsigned u[4] = {w.x, w.y, w.z, w.w};
    for (int k = 0; k < 4; ++k) {
      unsigned lo = u[k] & 0xFFFFu, hi = u[k] >> 16;
      if ((lo & 0x7F80u) == 0x7F80u) nanish++;
      if ((hi & 0x7F80u) == 0x7F80u) nanish++;
      if (lo == 0) zc++;
      if (hi == 0) zc++;
    }
  }
  __shared__ int rn[256], rz[256];
  rn[t] = nanish; rz[t] = zc;
  __syncthreads();
  for (int s = 128; s > 0; s >>= 1) {
    if (t < s) { rn[t] += rn[t + s]; rz[t] += rz[t + s]; }
    __syncthreads();
  }
  const int f = (rn[0] > 4 || rz[0] > 2048) ? 1 : 0;   // 1 = f32 inputs
  if (t == 0) flag[0] = f;
  for (int j = 0; j < 16; ++j) {
    int i = j * 256 + t;                               // 0..4095
    if (i < 3072)
      dq[i] = f ? ((const float*)sq)[i] : (float)((const bf16_t*)sq)[i];
    else {
      int k = i - 3072;
      dofs[k] = f ? ((const float*)so)[k] : (float)((const bf16_t*)so)[k];
    }
  }
}

// ------------------------------------------------------------- conv + transpose (fused)
// blocks 0..4095: x -> xb (8 bf16/thread). blocks 4096..8191: weight transpose,
// flattened (128 col-tiles x 32 row-tiles); col-tile <96 = w_qkv, >=96 = w_out.
__global__ __launch_bounds__(256) void conv_and_transpose(
    const void* __restrict__ x, bf16_t* __restrict__ xb,
    const void* __restrict__ w0, bf16_t* __restrict__ out0,
    const void* __restrict__ w1, bf16_t* __restrict__ out1,
    const int* __restrict__ flag) {
  const int bb = blockIdx.x;
  if (bb < 4096) {
    int i = (bb * 256 + threadIdx.x) * 8;
    if (flag[0]) {
      const float4* s = (const float4*)((const float*)x + i);
      float4 a = s[0], b = s[1];
      bf16_t* o = xb + i;
      o[0] = (bf16_t)a.x; o[1] = (bf16_t)a.y; o[2] = (bf16_t)a.z; o[3] = (bf16_t)a.w;
      o[4] = (bf16_t)b.x; o[5] = (bf16_t)b.y; o[6] = (bf16_t)b.z; o[7] = (bf16_t)b.w;
    } else {
      *(uint4*)(xb + i) = *(const uint4*)((const bf16_t*)x + i);
    }
    return;
  }
  __shared__ bf16_t tile[32][33];
  const int idx = bb - 4096;
  const int bxT = idx & 127, byT = idx >> 7;
  const int tx = threadIdx.x & 31, ty = threadIdx.x >> 5;
  const bool second = bxT >= 96;
  const void* in = second ? w1 : w0;
  bf16_t* out = second ? out1 : out0;
  const int C = second ? 1024 : 3072;
  const int R = 1024;
  const int c0 = (second ? (bxT - 96) : bxT) * 32;
  const int r0 = byT * 32;
  if (flag[0]) {
    for (int i = 0; i < 4; ++i) {
      int r = ty + i * 8;
      tile[r][tx] = (bf16_t)((const float*)in)[(size_t)(r0 + r) * C + c0 + tx];
    }
  } else {
    for (int i = 0; i < 4; ++i) {
      int r = ty + i * 8;
      tile[r][tx] = ((const bf16_t*)in)[(size_t)(r0 + r) * C + c0 + tx];
    }
  }
  __syncthreads();
  for (int i = 0; i < 4; ++i) {
    int r = ty + i * 8;
    out[(size_t)(c0 + r) * R + r0 + tx] = tile[tx][r];
  }
}

// ------------------------------------------------------------- 128x256 GEMM (B^T)
// R19 structure: grid (N/256, M/128); 512 thr = 8 waves (2M x 4N); per-wave
// 64x64 = acc[4][4]. K-tile BK=64 = 2 half-groups; per group: A [128][32] (8KB)
// + B [256][32]x2 (16KB) = 3 loads/thread. LDS = 3 x 48KB tile buffers (144KB,
// 1 block/CU). Group n+4 staged at phase n (3-phase distance > HBM latency);
// counted vmcnt(9) drains exactly group n+1. Tail: vmcnt(6/3/0). XOR swizzle
// byte ^= ((row&8)<<1)|((row&4)<<3) on reads; gload_lds dest linear, source
// k-chunk pre-inverse-swizzled (same involution).
// Race-safety: STG at phase n writes buf (T+2)%3; phases n,n+1 read bufs
// T%3/(T+1)%3 — never equal; prior readers of that buf retired 2 barriers ago.
// MODE 2 (QKV): bias; Q cols (<1024) x CEXP; V cols (>=2048) -> vT scatter.
// MODE 1 (out-proj): bias; dyn f32/bf16 store per flag.
template <int MODE>
__global__ __launch_bounds__(512) void gemm_v2(
    const bf16_t* __restrict__ A, const bf16_t* __restrict__ Bt,
    const float* __restrict__ bias, void* __restrict__ Cout,
    int M, int N, int K, bf16_t* __restrict__ vT,
    const int* __restrict__ flag) {
  __shared__ __align__(16) char smem[147456];   // 3 x 48KB
  char* lds = smem;
  const int t = threadIdx.x;
  const int wave = t >> 6, lane = t & 63;
  const int quad = lane >> 4, l16 = lane & 15;
  const int wr = wave >> 2, wc = wave & 3;     // 2M x 4N
  const int nwg = gridDim.x * gridDim.y;       // %8==0 for our grids
  const int lin = blockIdx.y * gridDim.x + blockIdx.x;
  const int cpx = nwg >> 3;
  const int swzb = (lin & 7) * cpx + (lin >> 3);
  const int bx = swzb % gridDim.x, by = swzb / gridDim.x;
  const int bM = by * 128, bN = bx * 256;

  const int srow = t >> 2;
  const int xr = ((srow >> 3) & 1) | (((srow >> 2) & 1) << 1);
  const int skl = ((t ^ xr) & 3) * 8;
  const size_t offA = (size_t)(bM + srow) * K + skl;
  const size_t offB = (size_t)(bN + srow) * K + skl;
  const size_t offB2 = offB + (size_t)128 * K;

#define STG(g) do {                                                            \
    const int tile_ = (g) >> 1, half_ = (g) & 1;                               \
    const int kk_ = tile_ * 64 + half_ * 32;                                   \
    char* base_ = lds + 49152 * (tile_ % 3);                                   \
    async_ld16(base_ + half_ * 8192 + t * 16, A + offA + kk_);                 \
    async_ld16(base_ + 16384 + half_ * 16384 + t * 16, Bt + offB + kk_);       \
    async_ld16(base_ + 16384 + half_ * 16384 + 8192 + t * 16,                  \
               Bt + offB2 + kk_); } while (0)

  int aoff[4], boff[4];
#pragma unroll
  for (int mf = 0; mf < 4; ++mf) {
    int r = wr * 64 + mf * 16 + l16;           // 0..127
    aoff[mf] = ((r << 6) + (quad << 4)) ^ (((r & 8) << 1) | ((r & 4) << 3));
  }
#pragma unroll
  for (int nf = 0; nf < 4; ++nf) {
    int r = wc * 64 + nf * 16 + l16;           // 0..255
    boff[nf] = ((r << 6) + (quad << 4)) ^ (((r & 8) << 1) | ((r & 4) << 3));
  }

  f32x4 acc[4][4] = {};
  const int NT = K >> 6;                       // 16 tiles, 32 groups

  STG(0); STG(1); STG(2); STG(3);
  asm volatile("s_waitcnt vmcnt(9)" ::: "memory");   // group 0 landed
  __builtin_amdgcn_s_barrier();
  asm volatile("" ::: "memory");

#define PHASE(T, h) do {                                                       \
    const int bufo_ = ((T) % 3) * 49152;                                       \
    bf16x8 af[4], bf[4];                                                       \
    _Pragma("unroll") for (int i_ = 0; i_ < 4; ++i_)                           \
      af[i_] = *(const bf16x8*)(lds + bufo_ + (h) * 8192 + aoff[i_]);          \
    _Pragma("unroll") for (int j_ = 0; j_ < 4; ++j_)                           \
      bf[j_] = *(const bf16x8*)(lds + bufo_ + 16384 + (h) * 16384 + boff[j_]); \
    const int n_ = 2 * (T) + (h);                                              \
    if (n_ + 4 < 2 * NT) {                                                     \
      STG(n_ + 4);                                                             \
      asm volatile("s_waitcnt vmcnt(9)" ::: "memory");                         \
    } else if (n_ == 2 * NT - 4) {                                             \
      asm volatile("s_waitcnt vmcnt(6)" ::: "memory");                         \
    } else if (n_ == 2 * NT - 3) {                                             \
      asm volatile("s_waitcnt vmcnt(3)" ::: "memory");                         \
    } else if (n_ == 2 * NT - 2) {                                             \
      asm volatile("s_waitcnt vmcnt(0)" ::: "memory");                         \
    }                                                                          \
    __builtin_amdgcn_s_barrier();                                              \
    asm volatile("" ::: "memory");                                             \
    __builtin_amdgcn_s_setprio(1);                                             \
    _Pragma("unroll") for (int i_ = 0; i_ < 4; ++i_)                           \
      { _Pragma("unroll") for (int j_ = 0; j_ < 4; ++j_)                       \
        acc[i_][j_] = __builtin_amdgcn_mfma_f32_16x16x32_bf16(                 \
            af[i_], bf[j_], acc[i_][j_], 0, 0, 0); }                           \
    __builtin_amdgcn_s_setprio(0);                                             \
    asm volatile("" ::: "memory");                                             \
    __builtin_amdgcn_s_barrier(); } while (0)

  for (int T = 0; T < NT; ++T) {
    PHASE(T, 0);
    PHASE(T, 1);
  }

  const bool f32out = (MODE == 1) && flag[0];
#pragma unroll
  for (int nf = 0; nf < 4; ++nf) {
    int col = bN + wc * 64 + nf * 16 + l16;
    float bv = bias[col];
#pragma unroll
    for (int mf = 0; mf < 4; ++mf) {
      int row0 = bM + wr * 64 + mf * 16 + quad * 4;
      if (MODE == 2 && col >= 2048) {
        int hh = (col - 2048) >> 6, dd = (col - 2048) & 63;
        bf16_t o4[4];
        for (int r = 0; r < 4; ++r) o4[r] = (bf16_t)(acc[mf][nf][r] + bv);
        size_t dst = ((((size_t)(row0 >> 11) * NH + hh) * HD + dd) << 11) | (row0 & 2047);
        *(uint2*)&vT[dst] = *(uint2*)o4;
      } else if (MODE == 2) {
        float scale = (col < 1024) ? CEXP : 1.0f;
        for (int r = 0; r < 4; ++r)
          ((bf16_t*)Cout)[(size_t)(row0 + r) * N + col] =
              (bf16_t)((acc[mf][nf][r] + bv) * scale);
      } else {
        for (int r = 0; r < 4; ++r) {
          float v = acc[mf][nf][r] + bv;
          if (f32out) ((float*)Cout)[(size_t)(row0 + r) * N + col] = v;
          else        ((bf16_t*)Cout)[(size_t)(row0 + r) * N + col] = (bf16_t)v;
        }
      }
    }
  }
#undef STG
#undef PHASE
}

// ------------------------------------------------------------- flash attention v12
// (verified 90.3-91.2us R7/R9/R10.) Grid (64, 8) x 512 thr; KVBLK=128; 64KB LDS
// dbuf; wave owns 32 q (2 subtiles). S^T via 16x16x32 (Q pre-scaled by CEXP);
// exp2 direct; PV via 16x16x16 from regs; softmax denominator on the MFMA pipe:
// lsum = MFMA(ones, P, lsum), epilogue reads lsum[0] (no shuffles).
// Mfma 56 + VALU 39 ~ issue-saturated; near this structure's ceiling.
__global__ __launch_bounds__(512) void attention_v12(
    const bf16_t* __restrict__ qkv, const bf16_t* __restrict__ vT,
    bf16_t* __restrict__ attn) {
  const int t = threadIdx.x;
  const int wave = t >> 6, lane = t & 63;           // wave 0..7
  const int quad = lane >> 4, l16 = lane & 15;
  const int bh = blockIdx.x, b = bh >> 4, h = bh & 15;
  const int qw = blockIdx.y * 256 + wave * 32;

  __shared__ bf16_t Kt[2][128 * 64];   // [key][d], 16B-chunk XOR swizzle by key&7
  __shared__ bf16_t Vt[2][64 * 128];   // [d][key], 16B-chunk XOR swizzle by d&15

  const bf16_t* qglob = qkv + (size_t)b * SEQ * 3072 + h * 64;
  const bf16_t* kglob = qglob + 1024;
  const bf16_t* vglob = vT + (size_t)bh * HD * SEQ;

  bf16x8 qf[2][2];
  for (int s = 0; s < 2; ++s) {
    const bf16_t* qrow = qglob + (size_t)(qw + s * 16 + l16) * 3072 + quad * 8;
    qf[s][0] = *(const bf16x8*)qrow;
    qf[s][1] = *(const bf16x8*)(qrow + 32);
  }

  f32x4 accO[2][4] = {};
  f32x4 lsum[2] = {};                       // denominator via ones-MFMA
  const short4v ones4 = {(short)0x3F80, (short)0x3F80, (short)0x3F80, (short)0x3F80};

  const int kRow = lane >> 3, kSlot = lane & 7;
  const int vRow = lane >> 4, vSlot = lane & 15;

  auto stageKV = [&](int buf, int kt) {
    for (int j = 0; j < 2; ++j) {   // K: wave stages keys [wave*16, +16)
      int keyl = wave * 16 + j * 8 + kRow;
      int gc = kSlot ^ (keyl & 7);
      async_ld16((char*)Kt[buf] + (wave * 16 + j * 8) * 128,
                 kglob + (size_t)(kt + keyl) * 3072 + gc * 8);
    }
    for (int j = 0; j < 2; ++j) {   // V: wave stages d [wave*8, +8)
      int d = wave * 8 + j * 4 + vRow;
      int gc = vSlot ^ (d & 15);
      async_ld16((char*)Vt[buf] + (wave * 8 + j * 4) * 256,
                 vglob + (size_t)d * SEQ + kt + gc * 8);
    }
  };

  stageKV(0, 0);

  for (int ti = 0; ti < SEQ / 128; ++ti) {
    const int buf = ti & 1;
    __syncthreads();                       // drain this tile's DMA + publish
    if (ti + 1 < SEQ / 128) stageKV(buf ^ 1, (ti + 1) * 128);

    const bf16_t* KtB = Kt[buf];
    const bf16_t* VtB = Vt[buf];

    for (int kb = 0; kb < 8; ++kb) {
      const bf16_t* kr = &KtB[(kb * 16 + l16) * 64];
      bf16x8 kf0 = *(const bf16x8*)(kr + ((quad ^ (l16 & 7)) * 8));
      bf16x8 kf1 = *(const bf16x8*)(kr + (((4 + quad) ^ (l16 & 7)) * 8));

      short4v pB[2];
      for (int s = 0; s < 2; ++s) {
        f32x4 z = {0.f, 0.f, 0.f, 0.f};
        f32x4 st = __builtin_amdgcn_mfma_f32_16x16x32_bf16(kf0, qf[s][0], z, 0, 0, 0);
        st = __builtin_amdgcn_mfma_f32_16x16x32_bf16(kf1, qf[s][1], st, 0, 0, 0);
        union { bf16_t hh[4]; short4v s4; } u;
        for (int r = 0; r < 4; ++r) {
          float p = __builtin_amdgcn_exp2f(st[r]);   // Q pre-scaled by CEXP
          u.hh[r] = (bf16_t)p;
        }
        pB[s] = u.s4;
        lsum[s] = MFMA_PV(ones4, pB[s], lsum[s]);    // denominator on MFMA pipe
      }

      const int chunkbase = kb * 2 + (quad >> 1);
      const int coff = (quad & 1) * 4;
      for (int db = 0; db < 4; ++db) {
        short4v vf = *(const short4v*)&VtB[(db * 16 + l16) * 128 +
                                           ((chunkbase ^ l16) * 8) + coff];
        for (int s = 0; s < 2; ++s)
          accO[s][db] = MFMA_PV(vf, pB[s], accO[s][db]);
      }
    }
  }

  for (int s = 0; s < 2; ++s) {
    float inv = 1.f / lsum[s][0];          // all rows identical; no shuffles
    size_t tok = (size_t)b * SEQ + qw + s * 16 + l16;
    for (int db = 0; db < 4; ++db) {
      bf16_t o4[4];
      for (int r = 0; r < 4; ++r) o4[r] = (bf16_t)(accO[s][db][r] * inv);
      *(uint2*)&attn[tok * DMODEL + h * HD + db * 16 + quad * 4] = *(uint2*)o4;
    }
  }
}

// ------------------------------------------------------------- launch
extern "C" void kernel_launch(void* const* d_in, const int* in_sizes, int n_in,
                              void* d_out, int out_size, void* d_ws, size_t ws_size,
                              hipStream_t stream) {
  const void* x     = d_in[0];
  const void* w_qkv = d_in[1];
  const void* b_qkv = d_in[2];
  const void* w_out = d_in[3];
  const void* b_out = d_in[4];

  char* ws = (char*)d_ws;
  int*    flag  = (int*)ws;                                    // @0
  bf16_t* wqkvT = (bf16_t*)(ws + 4096);                        // 6.0 MB
  bf16_t* woutT = (bf16_t*)(ws + 6295552);                     // 2.0 MB
  float*  bqkvf = (float*)(ws + 8392704);
  float*  boutf = (float*)(ws + 8404992);
  bf16_t* qkv   = (bf16_t*)(ws + 8409088);                     // 8192x3072 bf16 (50.3 MB)
  bf16_t* xb    = (bf16_t*)(ws + 58740736);                    // 16.8 MB
  bf16_t* attn  = xb;                                          // alias (xb dead after gemm1)
  bf16_t* vTbuf = (bf16_t*)(ws + 75517952);                    // 16.8 MB -> end ~92.3 MB

  sniff_dtype<<<1, 256, 0, stream>>>((const uint4*)x, flag, b_qkv, b_out,
                                     bqkvf, boutf);

  conv_and_transpose<<<8192, 256, 0, stream>>>(x, xb, w_qkv, wqkvT, w_out, woutT,
                                               flag);

  gemm_v2<2><<<dim3(12, 64), 512, 0, stream>>>(
      xb, wqkvT, bqkvf, qkv, NTOK, 3072, 1024, vTbuf, flag);

  attention_v12<<<dim3(BATCH * NH, SEQ / 256), 512, 0, stream>>>(qkv, vTbuf, attn);

  gemm_v2<1><<<dim3(4, 64), 512, 0, stream>>>(
      attn, woutT, boutf, d_out, NTOK, 1024, 1024, nullptr, flag);
}

// Round 12
// 277.393 us; speedup vs baseline: 1.0173x; 1.0173x over previous
//
#include <hip/hip_runtime.h>
#include <hip/hip_bf16.h>

// MHA forward. B=4, T=2048, D=1024, H=16, Hd=64. Inputs auto-detected f32/bf16.
// convert x + transpose weights (fused) -> QKV GEMM (128x256/BK64 2-buf depth-3
// prefetch, 2D-L2-locality XCD swizzle; +bias; Q pre-scaled by log2e/8; V -> vT
// in-epilogue) -> flash attention v12 (KVBLK=128, lsum via ones-MFMA) -> out
// GEMM (same template, dyn f32/bf16 out).
// R4: never cap occupancy via __launch_bounds__ 2nd arg (spill disaster).
// R5: don't interleave P LDS writes into PV chain. R6: keep S live range to one kb.
// R7: all single-buffer variants stall ~120us on per-tile barrier drain.
// R9: manual instr-order pinning defeats compiler sched (m141).
// R10: no-LDS attention REGRESSED 3.5x: K-row stride 6KB; LDS IS the coalescer.
// R12: lp-as-f32x4 REGRESSED: acc vectorization perturbed regalloc.
// R15: lsum-via-ones-MFMA WIN: attn 101->90.3, Mfma 43.7->56.9 (+VALU ~ 96%
//     issue-saturated -> v12 near this structure's ceiling). VGPR 88->60.
// R16: KVBLK=64 FAILED: grid only 512 blocks -> still 2 resident/CU.
// R17: gemm1 128x256/BK64 768 blocks = 3 exact rounds: -6us. R18: gemm2: -2us.
// R19: triple-buffer depth-4 prefetch REGRESSED (+4us): NOT latency-bound.
//     Traffic arithmetic: 576MB panel traffic / 74us = 7.8 TB/s from L2/L3
//     fabric (HBM counter only 1.5 TB/s) -> GEMM is L2/L3-BANDWIDTH-bound.
//     Explains ~600TF convergence across all tile structures + prefetch nulls.
// R20 (this round): revert to R10 2-buf depth-3 (verified 278.3us) + 2D
//     super-tile XCD swizzle: XCD k owns a gridDim.x x 8 tile region walked in
//     4-wide bx chunks -> concurrent per-XCD working set = 4 B-panels (2MB) +
//     8 A-panels (2MB) = 4MB = one L2 (1D row-sweep had 6MB of B thrashing L2).

typedef __bf16 bf16_t;
typedef __bf16 bf16x8 __attribute__((ext_vector_type(8)));
typedef float f32x4 __attribute__((ext_vector_type(4)));
typedef short short4v __attribute__((ext_vector_type(4)));

#if __has_builtin(__builtin_amdgcn_mfma_f32_16x16x16_bf16)
typedef __bf16 bf16x4 __attribute__((ext_vector_type(4)));
#define MFMA_PV(va, vb, c) __builtin_amdgcn_mfma_f32_16x16x16_bf16( \
    __builtin_bit_cast(bf16x4, (va)), __builtin_bit_cast(bf16x4, (vb)), (c), 0, 0, 0)
#else
#define MFMA_PV(va, vb, c) __builtin_amdgcn_mfma_f32_16x16x16bf16_1k((va), (vb), (c), 0, 0, 0)
#endif

#define DMODEL 1024
#define NH     16
#define HD     64
#define BATCH  4
#define SEQ    2048
#define NTOK   (BATCH * SEQ)      // 8192
#define NOUT   (NTOK * DMODEL)    // 8388608
#define CEXP   0.1803368801111204f   // log2(e)/sqrt(64)

__device__ __forceinline__ void async_ld16(void* lds, const void* g) {
  __builtin_amdgcn_global_load_lds(
      (const __attribute__((address_space(1))) void*)g,
      (__attribute__((address_space(3))) void*)lds, 16, 0, 0);
}

// ------------------------------------------------------------- dtype sniff + biases
__global__ __launch_bounds__(256) void sniff_dtype(
    const uint4* __restrict__ x, int* __restrict__ flag,
    const void* __restrict__ sq, const void* __restrict__ so,
    float* __restrict__ dq, float* __restrict__ dofs) {
  int t = threadIdx.x;
  int nanish = 0, zc = 0;
  for (int j = 0; j < 4; ++j) {
    uint4 w = x[t + j * 256];
    unsigned u[4] = {w.x, w.y, w.z, w.w};
    for (int k = 0; k < 4; ++k) {
      unsigned lo = u[k] & 0xFFFFu, hi = u[k] >> 16;
      if ((lo & 0x7F80u) == 0x7F80u) nanish++;
      if ((hi & 0x7F80u) == 0x7F80u) nanish++;
      if (lo == 0) zc++;
      if (hi == 0) zc++;
    }
  }
  __shared__ int rn[256], rz[256];
  rn[t] = nanish; rz[t] = zc;
  __syncthreads();
  for (int s = 128; s > 0; s >>= 1) {
    if (t < s) { rn[t] += rn[t + s]; rz[t] += rz[t + s]; }
    __syncthreads();
  }
  const int f = (rn[0] > 4 || rz[0] > 2048) ? 1 : 0;   // 1 = f32 inputs
  if (t == 0) flag[0] = f;
  for (int j = 0; j < 16; ++j) {
    int i = j * 256 + t;                               // 0..4095
    if (i < 3072)
      dq[i] = f ? ((const float*)sq)[i] : (float)((const bf16_t*)sq)[i];
    else {
      int k = i - 3072;
      dofs[k] = f ? ((const float*)so)[k] : (float)((const bf16_t*)so)[k];
    }
  }
}

// ------------------------------------------------------------- conv + transpose (fused)
// blocks 0..4095: x -> xb (8 bf16/thread). blocks 4096..8191: weight transpose,
// flattened (128 col-tiles x 32 row-tiles); col-tile <96 = w_qkv, >=96 = w_out.
__global__ __launch_bounds__(256) void conv_and_transpose(
    const void* __restrict__ x, bf16_t* __restrict__ xb,
    const void* __restrict__ w0, bf16_t* __restrict__ out0,
    const void* __restrict__ w1, bf16_t* __restrict__ out1,
    const int* __restrict__ flag) {
  const int bb = blockIdx.x;
  if (bb < 4096) {
    int i = (bb * 256 + threadIdx.x) * 8;
    if (flag[0]) {
      const float4* s = (const float4*)((const float*)x + i);
      float4 a = s[0], b = s[1];
      bf16_t* o = xb + i;
      o[0] = (bf16_t)a.x; o[1] = (bf16_t)a.y; o[2] = (bf16_t)a.z; o[3] = (bf16_t)a.w;
      o[4] = (bf16_t)b.x; o[5] = (bf16_t)b.y; o[6] = (bf16_t)b.z; o[7] = (bf16_t)b.w;
    } else {
      *(uint4*)(xb + i) = *(const uint4*)((const bf16_t*)x + i);
    }
    return;
  }
  __shared__ bf16_t tile[32][33];
  const int idx = bb - 4096;
  const int bxT = idx & 127, byT = idx >> 7;
  const int tx = threadIdx.x & 31, ty = threadIdx.x >> 5;
  const bool second = bxT >= 96;
  const void* in = second ? w1 : w0;
  bf16_t* out = second ? out1 : out0;
  const int C = second ? 1024 : 3072;
  const int R = 1024;
  const int c0 = (second ? (bxT - 96) : bxT) * 32;
  const int r0 = byT * 32;
  if (flag[0]) {
    for (int i = 0; i < 4; ++i) {
      int r = ty + i * 8;
      tile[r][tx] = (bf16_t)((const float*)in)[(size_t)(r0 + r) * C + c0 + tx];
    }
  } else {
    for (int i = 0; i < 4; ++i) {
      int r = ty + i * 8;
      tile[r][tx] = ((const bf16_t*)in)[(size_t)(r0 + r) * C + c0 + tx];
    }
  }
  __syncthreads();
  for (int i = 0; i < 4; ++i) {
    int r = ty + i * 8;
    out[(size_t)(c0 + r) * R + r0 + tx] = tile[tx][r];
  }
}

// ------------------------------------------------------------- 128x256 GEMM (B^T)
// R10-verified pipeline (2-buf, depth-3 groups, vmcnt(6)) + R20 2D swizzle.
// Grid (N/256, M/128); 512 thr = 8 waves (2M x 4N); per-wave 64x64 = acc[4][4].
// K-tile BK=64 = 2 half-groups; per group: A [128][32] (8KB) + B [256][32]x2
// (16KB) = 3 loads/thread. 2-tile dbuf = 96KB. Group n+3 staged at phase n;
// counted vmcnt(6)/phase; tail vmcnt(3)/vmcnt(0). XOR swizzle
// byte ^= ((row&8)<<1)|((row&4)<<3) on reads; gload_lds dest linear, source
// k-chunk pre-inverse-swizzled (same involution).
// 2D XCD swizzle: XCD k = hw_id&7 owns a (gridDim.x x R) tile region
// (R = nwg/8/gridDim.x), walked in CW=4-wide bx chunks -> 32 concurrent
// blocks touch 4 B-panels + 8 A-panels = 4MB = one L2.
// MODE 2 (QKV): bias; Q cols (<1024) x CEXP; V cols (>=2048) -> vT scatter.
// MODE 1 (out-proj): bias; dyn f32/bf16 store per flag.
template <int MODE>
__global__ __launch_bounds__(512) void gemm_v2(
    const bf16_t* __restrict__ A, const bf16_t* __restrict__ Bt,
    const float* __restrict__ bias, void* __restrict__ Cout,
    int M, int N, int K, bf16_t* __restrict__ vT,
    const int* __restrict__ flag) {
  __shared__ __align__(16) char smem[98304];
  char* lds = smem;
  const int t = threadIdx.x;
  const int wave = t >> 6, lane = t & 63;
  const int quad = lane >> 4, l16 = lane & 15;
  const int wr = wave >> 2, wc = wave & 3;     // 2M x 4N
  // 2D L2-locality XCD swizzle (bijective for both grids; perf-only).
  const int lin = blockIdx.y * gridDim.x + blockIdx.x;
  const int xcd = lin & 7;
  const int slot = lin >> 3;                   // 0..nwg/8-1
  const int Rrows = ((gridDim.x * gridDim.y) >> 3) / gridDim.x;  // by-rows/XCD
  const int CW = gridDim.x < 4 ? gridDim.x : 4;
  const int CB = CW * Rrows;                   // blocks per chunk
  const int chunk = slot / CB, within = slot % CB;
  const int bx = chunk * CW + within % CW;
  const int by = xcd * Rrows + within / CW;
  const int bM = by * 128, bN = bx * 256;

  const int srow = t >> 2;
  const int xr = ((srow >> 3) & 1) | (((srow >> 2) & 1) << 1);
  const int skl = ((t ^ xr) & 3) * 8;
  const size_t offA = (size_t)(bM + srow) * K + skl;
  const size_t offB = (size_t)(bN + srow) * K + skl;
  const size_t offB2 = offB + (size_t)128 * K;

#define STG(g) do {                                                            \
    const int tile_ = (g) >> 1, half_ = (g) & 1;                               \
    const int kk_ = tile_ * 64 + half_ * 32;                                   \
    char* base_ = lds + ((tile_ & 1) ? 49152 : 0);                             \
    async_ld16(base_ + half_ * 8192 + t * 16, A + offA + kk_);                 \
    async_ld16(base_ + 16384 + half_ * 16384 + t * 16, Bt + offB + kk_);       \
    async_ld16(base_ + 16384 + half_ * 16384 + 8192 + t * 16,                  \
               Bt + offB2 + kk_); } while (0)

  int aoff[4], boff[4];
#pragma unroll
  for (int mf = 0; mf < 4; ++mf) {
    int r = wr * 64 + mf * 16 + l16;           // 0..127
    aoff[mf] = ((r << 6) + (quad << 4)) ^ (((r & 8) << 1) | ((r & 4) << 3));
  }
#pragma unroll
  for (int nf = 0; nf < 4; ++nf) {
    int r = wc * 64 + nf * 16 + l16;           // 0..255
    boff[nf] = ((r << 6) + (quad << 4)) ^ (((r & 8) << 1) | ((r & 4) << 3));
  }

  f32x4 acc[4][4] = {};
  const int NT = K >> 6;                       // 16 tiles, 32 groups

  STG(0); STG(1); STG(2);
  asm volatile("s_waitcnt vmcnt(6)" ::: "memory");
  __builtin_amdgcn_s_barrier();
  asm volatile("" ::: "memory");

#define PHASE(T, h) do {                                                       \
    const int bufo_ = ((T) & 1) * 49152;                                       \
    bf16x8 af[4], bf[4];                                                       \
    _Pragma("unroll") for (int i_ = 0; i_ < 4; ++i_)                           \
      af[i_] = *(const bf16x8*)(lds + bufo_ + (h) * 8192 + aoff[i_]);          \
    _Pragma("unroll") for (int j_ = 0; j_ < 4; ++j_)                           \
      bf[j_] = *(const bf16x8*)(lds + bufo_ + 16384 + (h) * 16384 + boff[j_]); \
    const int n_ = 2 * (T) + (h);                                              \
    if (n_ + 3 < 2 * NT) {                                                     \
      STG(n_ + 3);                                                             \
      asm volatile("s_waitcnt vmcnt(6)" ::: "memory");                         \
    } else if (n_ == 2 * NT - 3) {                                             \
      asm volatile("s_waitcnt vmcnt(3)" ::: "memory");                         \
    } else if (n_ == 2 * NT - 2) {                                             \
      asm volatile("s_waitcnt vmcnt(0)" ::: "memory");                         \
    }                                                                          \
    __builtin_amdgcn_s_barrier();                                              \
    asm volatile("" ::: "memory");                                             \
    __builtin_amdgcn_s_setprio(1);                                             \
    _Pragma("unroll") for (int i_ = 0; i_ < 4; ++i_)                           \
      { _Pragma("unroll") for (int j_ = 0; j_ < 4; ++j_)                       \
        acc[i_][j_] = __builtin_amdgcn_mfma_f32_16x16x32_bf16(                 \
            af[i_], bf[j_], acc[i_][j_], 0, 0, 0); }                           \
    __builtin_amdgcn_s_setprio(0);                                             \
    asm volatile("" ::: "memory");                                             \
    __builtin_amdgcn_s_barrier(); } while (0)

  for (int T = 0; T < NT; ++T) {
    PHASE(T, 0);
    PHASE(T, 1);
  }

  const bool f32out = (MODE == 1) && flag[0];
#pragma unroll
  for (int nf = 0; nf < 4; ++nf) {
    int col = bN + wc * 64 + nf * 16 + l16;
    float bv = bias[col];
#pragma unroll
    for (int mf = 0; mf < 4; ++mf) {
      int row0 = bM + wr * 64 + mf * 16 + quad * 4;
      if (MODE == 2 && col >= 2048) {
        int hh = (col - 2048) >> 6, dd = (col - 2048) & 63;
        bf16_t o4[4];
        for (int r = 0; r < 4; ++r) o4[r] = (bf16_t)(acc[mf][nf][r] + bv);
        size_t dst = ((((size_t)(row0 >> 11) * NH + hh) * HD + dd) << 11) | (row0 & 2047);
        *(uint2*)&vT[dst] = *(uint2*)o4;
      } else if (MODE == 2) {
        float scale = (col < 1024) ? CEXP : 1.0f;
        for (int r = 0; r < 4; ++r)
          ((bf16_t*)Cout)[(size_t)(row0 + r) * N + col] =
              (bf16_t)((acc[mf][nf][r] + bv) * scale);
      } else {
        for (int r = 0; r < 4; ++r) {
          float v = acc[mf][nf][r] + bv;
          if (f32out) ((float*)Cout)[(size_t)(row0 + r) * N + col] = v;
          else        ((bf16_t*)Cout)[(size_t)(row0 + r) * N + col] = (bf16_t)v;
        }
      }
    }
  }
#undef STG
#undef PHASE
}

// ------------------------------------------------------------- flash attention v12
// (verified 90-91us R7/R9/R10/R11.) Grid (64, 8) x 512 thr; KVBLK=128; 64KB LDS
// dbuf; wave owns 32 q (2 subtiles). S^T via 16x16x32 (Q pre-scaled by CEXP);
// exp2 direct; PV via 16x16x16 from regs; softmax denominator on the MFMA pipe:
// lsum = MFMA(ones, P, lsum), epilogue reads lsum[0] (no shuffles).
// Mfma 56 + VALU 39 ~ issue-saturated; near this structure's ceiling.
__global__ __launch_bounds__(512) void attention_v12(
    const bf16_t* __restrict__ qkv, const bf16_t* __restrict__ vT,
    bf16_t* __restrict__ attn) {
  const int t = threadIdx.x;
  const int wave = t >> 6, lane = t & 63;           // wave 0..7
  const int quad = lane >> 4, l16 = lane & 15;
  const int bh = blockIdx.x, b = bh >> 4, h = bh & 15;
  const int qw = blockIdx.y * 256 + wave * 32;

  __shared__ bf16_t Kt[2][128 * 64];   // [key][d], 16B-chunk XOR swizzle by key&7
  __shared__ bf16_t Vt[2][64 * 128];   // [d][key], 16B-chunk XOR swizzle by d&15

  const bf16_t* qglob = qkv + (size_t)b * SEQ * 3072 + h * 64;
  const bf16_t* kglob = qglob + 1024;
  const bf16_t* vglob = vT + (size_t)bh * HD * SEQ;

  bf16x8 qf[2][2];
  for (int s = 0; s < 2; ++s) {
    const bf16_t* qrow = qglob + (size_t)(qw + s * 16 + l16) * 3072 + quad * 8;
    qf[s][0] = *(const bf16x8*)qrow;
    qf[s][1] = *(const bf16x8*)(qrow + 32);
  }

  f32x4 accO[2][4] = {};
  f32x4 lsum[2] = {};                       // denominator via ones-MFMA
  const short4v ones4 = {(short)0x3F80, (short)0x3F80, (short)0x3F80, (short)0x3F80};

  const int kRow = lane >> 3, kSlot = lane & 7;
  const int vRow = lane >> 4, vSlot = lane & 15;

  auto stageKV = [&](int buf, int kt) {
    for (int j = 0; j < 2; ++j) {   // K: wave stages keys [wave*16, +16)
      int keyl = wave * 16 + j * 8 + kRow;
      int gc = kSlot ^ (keyl & 7);
      async_ld16((char*)Kt[buf] + (wave * 16 + j * 8) * 128,
                 kglob + (size_t)(kt + keyl) * 3072 + gc * 8);
    }
    for (int j = 0; j < 2; ++j) {   // V: wave stages d [wave*8, +8)
      int d = wave * 8 + j * 4 + vRow;
      int gc = vSlot ^ (d & 15);
      async_ld16((char*)Vt[buf] + (wave * 8 + j * 4) * 256,
                 vglob + (size_t)d * SEQ + kt + gc * 8);
    }
  };

  stageKV(0, 0);

  for (int ti = 0; ti < SEQ / 128; ++ti) {
    const int buf = ti & 1;
    __syncthreads();                       // drain this tile's DMA + publish
    if (ti + 1 < SEQ / 128) stageKV(buf ^ 1, (ti + 1) * 128);

    const bf16_t* KtB = Kt[buf];
    const bf16_t* VtB = Vt[buf];

    for (int kb = 0; kb < 8; ++kb) {
      const bf16_t* kr = &KtB[(kb * 16 + l16) * 64];
      bf16x8 kf0 = *(const bf16x8*)(kr + ((quad ^ (l16 & 7)) * 8));
      bf16x8 kf1 = *(const bf16x8*)(kr + (((4 + quad) ^ (l16 & 7)) * 8));

      short4v pB[2];
      for (int s = 0; s < 2; ++s) {
        f32x4 z = {0.f, 0.f, 0.f, 0.f};
        f32x4 st = __builtin_amdgcn_mfma_f32_16x16x32_bf16(kf0, qf[s][0], z, 0, 0, 0);
        st = __builtin_amdgcn_mfma_f32_16x16x32_bf16(kf1, qf[s][1], st, 0, 0, 0);
        union { bf16_t hh[4]; short4v s4; } u;
        for (int r = 0; r < 4; ++r) {
          float p = __builtin_amdgcn_exp2f(st[r]);   // Q pre-scaled by CEXP
          u.hh[r] = (bf16_t)p;
        }
        pB[s] = u.s4;
        lsum[s] = MFMA_PV(ones4, pB[s], lsum[s]);    // denominator on MFMA pipe
      }

      const int chunkbase = kb * 2 + (quad >> 1);
      const int coff = (quad & 1) * 4;
      for (int db = 0; db < 4; ++db) {
        short4v vf = *(const short4v*)&VtB[(db * 16 + l16) * 128 +
                                           ((chunkbase ^ l16) * 8) + coff];
        for (int s = 0; s < 2; ++s)
          accO[s][db] = MFMA_PV(vf, pB[s], accO[s][db]);
      }
    }
  }

  for (int s = 0; s < 2; ++s) {
    float inv = 1.f / lsum[s][0];          // all rows identical; no shuffles
    size_t tok = (size_t)b * SEQ + qw + s * 16 + l16;
    for (int db = 0; db < 4; ++db) {
      bf16_t o4[4];
      for (int r = 0; r < 4; ++r) o4[r] = (bf16_t)(accO[s][db][r] * inv);
      *(uint2*)&attn[tok * DMODEL + h * HD + db * 16 + quad * 4] = *(uint2*)o4;
    }
  }
}

// ------------------------------------------------------------- launch
extern "C" void kernel_launch(void* const* d_in, const int* in_sizes, int n_in,
                              void* d_out, int out_size, void* d_ws, size_t ws_size,
                              hipStream_t stream) {
  const void* x     = d_in[0];
  const void* w_qkv = d_in[1];
  const void* b_qkv = d_in[2];
  const void* w_out = d_in[3];
  const void* b_out = d_in[4];

  char* ws = (char*)d_ws;
  int*    flag  = (int*)ws;                                    // @0
  bf16_t* wqkvT = (bf16_t*)(ws + 4096);                        // 6.0 MB
  bf16_t* woutT = (bf16_t*)(ws + 6295552);                     // 2.0 MB
  float*  bqkvf = (float*)(ws + 8392704);
  float*  boutf = (float*)(ws + 8404992);
  bf16_t* qkv   = (bf16_t*)(ws + 8409088);                     // 8192x3072 bf16 (50.3 MB)
  bf16_t* xb    = (bf16_t*)(ws + 58740736);                    // 16.8 MB
  bf16_t* attn  = xb;                                          // alias (xb dead after gemm1)
  bf16_t* vTbuf = (bf16_t*)(ws + 75517952);                    // 16.8 MB -> end ~92.3 MB

  sniff_dtype<<<1, 256, 0, stream>>>((const uint4*)x, flag, b_qkv, b_out,
                                     bqkvf, boutf);

  conv_and_transpose<<<8192, 256, 0, stream>>>(x, xb, w_qkv, wqkvT, w_out, woutT,
                                               flag);

  gemm_v2<2><<<dim3(12, 64), 512, 0, stream>>>(
      xb, wqkvT, bqkvf, qkv, NTOK, 3072, 1024, vTbuf, flag);

  attention_v12<<<dim3(BATCH * NH, SEQ / 256), 512, 0, stream>>>(qkv, vTbuf, attn);

  gemm_v2<1><<<dim3(4, 64), 512, 0, stream>>>(
      attn, woutT, boutf, d_out, NTOK, 1024, 1024, nullptr, flag);
}